// Round 1
// baseline (123.783 us; speedup 1.0000x reference)
//
#include <hip/hip_runtime.h>
#include <math.h>

// Round-robin tournament pairs for parallel Jacobi on 8 indices (p<q).
static __device__ const int RRp[7][4] = {
  {0,1,2,3},{0,5,1,2},{0,4,3,1},{0,3,2,1},{0,2,1,6},{0,1,4,5},{0,2,3,4}
};
static __device__ const int RRq[7][4] = {
  {7,6,5,4},{6,7,4,3},{5,6,7,2},{4,5,6,7},{3,4,5,7},{2,3,7,6},{1,7,6,5}
};

__device__ __forceinline__ double rdin(const void* p, int idx, bool isdbl) {
  return isdbl ? ((const double*)p)[idx] : (double)((const float*)p)[idx];
}

__global__ __launch_bounds__(256) void fi_pauli_kernel(
    const void* __restrict__ xv,
    const void* __restrict__ kv,
    const void* __restrict__ bv,
    float* __restrict__ out, int Bn)
{
  const int i = blockIdx.x;
  const int t = threadIdx.x;

  __shared__ double pw[64];
  __shared__ double Hre[8][8], Him[8][8];
  __shared__ double Vre[8][8], Vim[8][8];
  __shared__ double Fre[8][8], Fim[8][8];
  __shared__ double Gre[8][8], Gim[8][8];
  __shared__ double ampre[8], ampim[8], invPs[8], ev[8];
  __shared__ double gs[8][64], hs[8][64];
  __shared__ __align__(16) float Mf[64][68];   // stride 68 -> 16B-aligned float4 rows
  __shared__ float xf[4];

  // ---- runtime dtype detection (f32 vs f64 inputs) -------------------------
  // If x is really float64, every other 32-bit word is random double-mantissa
  // bits -> reinterpreted float has random exponent; P(all 32 low words look
  // sane) ~ 1e-8. True float32 N(0,1) data never exceeds 1e6.
  bool isdbl = false;
  {
    const float* xq = (const float*)xv;   // 1024 elements min => 64 floats safe
    for (int j = 0; j < 64; ++j) {
      float a = fabsf(xq[j]);
      if (!(a < 1e6f)) isdbl = true;      // catches big, inf, nan
    }
  }

  // ---- pw = x @ K + bias (fp64) -------------------------------------------
  if (t < 4) xf[t] = (float)rdin(xv, i*4 + t, isdbl);
  if (t < 64) {
    double acc = rdin(bv, t, isdbl);
    #pragma unroll
    for (int j = 0; j < 4; ++j)
      acc += rdin(xv, i*4 + j, isdbl) * rdin(kv, j*64 + t, isdbl);
    pw[t] = acc;
  }
  __syncthreads();

  // ---- build H = sum_k pw_k P_k (analytic Pauli strings), init V = I ------
  if (t < 64) {
    int r = t >> 3, c = t & 7;
    int m = r ^ c;                       // flip mask of contributing strings
    double hre = 0.0, him = 0.0;
    for (int u = 0; u < 8; ++u) {        // 8 strings share this flip mask
      int k = 0;
      double pr = 1.0, pim = 0.0;
      #pragma unroll
      for (int q = 0; q < 3; ++q) {      // q=0 acts on bit2 (first kron factor)
        int bit = 2 - q;
        int f  = (m >> bit) & 1;
        int ch = (u >> bit) & 1;
        int rb = (r >> bit) & 1;
        int d  = f ? (ch ? 2 : 1) : (ch ? 3 : 0);  // I=0,X=1,Y=2,Z=3
        k = (k << 2) | d;
        if (d == 2) {                    // Y: row0 -> -i, row1 -> +i
          double nr = rb ? -pim : pim;
          double ni = rb ?  pr  : -pr;
          pr = nr; pim = ni;
        } else if (d == 3 && rb) { pr = -pr; pim = -pim; }
      }
      double w = pw[k];
      hre += w * pr; him += w * pim;
    }
    Hre[r][c] = hre; Him[r][c] = him;
    Vre[r][c] = (r == c) ? 1.0 : 0.0;
    Vim[r][c] = 0.0;
  }
  __syncthreads();

  // ---- complex Hermitian Jacobi, parallel round-robin ordering ------------
  for (int sweep = 0; sweep < 6; ++sweep) {
    for (int round = 0; round < 7; ++round) {
      int tl = t & 31;
      int pp = tl >> 3, j = tl & 7;
      int p = RRp[round][pp], q = RRq[round][pp];
      double cc = 1.0, sg = 0.0, wr = 1.0, wi = 0.0;
      if (t < 64) {                      // rotation params from ORIGINAL H
        double a = Hre[p][p], b = Hre[q][q];
        double zr = Hre[p][q], zi = Him[p][q];
        double r2 = zr*zr + zi*zi;
        if (r2 > 1e-60) {
          double rr = sqrt(r2);
          wr = zr / rr; wi = zi / rr;
          double th = (b - a) / (2.0 * rr);
          double tt = ((th >= 0.0) ? 1.0 : -1.0) / (fabs(th) + sqrt(1.0 + th*th));
          cc = 1.0 / sqrt(1.0 + tt*tt);
          sg = tt * cc;
        }
      }
      __syncthreads();
      if (t < 32) {                      // H column update: A <- A*U
        double upr = Hre[j][p], upi = Him[j][p];
        double uqr = Hre[j][q], uqi = Him[j][q];
        Hre[j][p] = cc*upr - sg*(wr*uqr + wi*uqi);
        Him[j][p] = cc*upi - sg*(wr*uqi - wi*uqr);
        Hre[j][q] = sg*(wr*upr - wi*upi) + cc*uqr;
        Him[j][q] = sg*(wr*upi + wi*upr) + cc*uqi;
      } else if (t < 64) {               // V column update: V <- V*U
        double vpr = Vre[j][p], vpi = Vim[j][p];
        double vqr = Vre[j][q], vqi = Vim[j][q];
        Vre[j][p] = cc*vpr - sg*(wr*vqr + wi*vqi);
        Vim[j][p] = cc*vpi - sg*(wr*vqi - wi*vqr);
        Vre[j][q] = sg*(wr*vpr - wi*vpi) + cc*vqr;
        Vim[j][q] = sg*(wr*vpi + wi*vpr) + cc*vqi;
      }
      __syncthreads();
      if (t < 32) {                      // H row update: A <- U^H * A
        double rpr = Hre[p][j], rpi = Him[p][j];
        double rqr = Hre[q][j], rqi = Him[q][j];
        Hre[p][j] = cc*rpr - sg*(wr*rqr - wi*rqi);
        Him[p][j] = cc*rpi - sg*(wr*rqi + wi*rqr);
        Hre[q][j] = sg*(wr*rpr + wi*rpi) + cc*rqr;
        Him[q][j] = sg*(wr*rpi - wi*rpr) + cc*rqi;
      }
      __syncthreads();
    }
  }

  if (t < 8) ev[t] = Hre[t][t];
  __syncthreads();

  // ---- F matrix (Daleckii-Krein divided differences) + amp + 1/P ----------
  if (t < 64) {
    int s = t >> 3, u = t & 7;
    double dm = 0.5 * (ev[s] - ev[u]);
    double av = 0.5 * (ev[s] + ev[u]);
    double sc = (fabs(dm) < 1e-6) ? (1.0 - dm*dm*(1.0/6.0)) : (sin(dm)/dm);
    Fre[s][u] =  cos(av) * sc;
    Fim[s][u] = -sin(av) * sc;
  }
  if (t < 8) {                           // amp_j = sum_s V[j][s] conj(V[0][s]) e^{-i e_s}
    double are = 0.0, aim = 0.0;
    #pragma unroll
    for (int s = 0; s < 8; ++s) {
      double ce = cos(ev[s]), se = -sin(ev[s]);
      double c0r = Vre[0][s], c0i = -Vim[0][s];
      double wr2 = c0r*ce - c0i*se;
      double wi2 = c0r*se + c0i*ce;
      double vjr = Vre[t][s], vji = Vim[t][s];
      are += vjr*wr2 - vji*wi2;
      aim += vjr*wi2 + vji*wr2;
    }
    ampre[t] = are; ampim[t] = aim;
    double P = are*are + aim*aim;
    invPs[t] = 1.0 / fmax(P, 1e-300);
  }
  __syncthreads();

  // ---- G[s][rho] = sum_t V[rho][t] F[s][t] conj(V[0][t])  (k-independent) --
  if (t < 64) {
    int s = t >> 3, rho = t & 7;
    double gr = 0.0, gi = 0.0;
    #pragma unroll
    for (int u = 0; u < 8; ++u) {
      double c0r = Vre[0][u], c0i = -Vim[0][u];
      double fr = Fre[s][u], fi = Fim[s][u];
      double fcr = fr*c0r - fi*c0i;
      double fci = fr*c0i + fi*c0r;
      double vr = Vre[rho][u], vi = Vim[rho][u];
      gr += vr*fcr - vi*fci;
      gi += vr*fci + vi*fcr;
    }
    Gre[s][rho] = gr; Gim[s][rho] = gi;
  }
  __syncthreads();

  // ---- per-Pauli Jacobian column: thread k computes g[:,k] -----------------
  if (t < 64) {
    const int k = t;
    const int d0 = (k >> 4) & 3, d1 = (k >> 2) & 3, d2 = k & 3;
    const int m = ((((d0 == 1) | (d0 == 2)) ? 1 : 0) << 2)
                | ((((d1 == 1) | (d1 == 2)) ? 1 : 0) << 1)
                |  (((d2 == 1) | (d2 == 2)) ? 1 : 0);
    double yre[8], yim[8];
    #pragma unroll
    for (int s = 0; s < 8; ++s) { yre[s] = 0.0; yim[s] = 0.0; }
    for (int r = 0; r < 8; ++r) {
      double pr = 1.0, pim = 0.0;        // ph_k(r)
      const int dd0[3] = {d0, d1, d2};
      #pragma unroll
      for (int q = 0; q < 3; ++q) {
        int rb = (r >> (2 - q)) & 1;
        int d = dd0[q];
        if (d == 2) {
          double nr = rb ? -pim : pim;
          double ni = rb ?  pr  : -pr;
          pr = nr; pim = ni;
        } else if (d == 3 && rb) { pr = -pr; pim = -pim; }
      }
      int rm = r ^ m;
      #pragma unroll
      for (int s = 0; s < 8; ++s) {      // y_s += conj(V[r][s]) ph G[s][r^m]
        double vr = Vre[r][s], vi = -Vim[r][s];
        double gr2 = Gre[s][rm], gi2 = Gim[s][rm];
        double ar = pr*gr2 - pim*gi2;
        double ai = pr*gi2 + pim*gr2;
        yre[s] += vr*ar - vi*ai;
        yim[s] += vr*ai + vi*ar;
      }
    }
    for (int p = 0; p < 8; ++p) {        // damp_p = sum_s V[p][s] * (-i*y_s)
      double dr = 0.0, di = 0.0;
      #pragma unroll
      for (int s = 0; s < 8; ++s) {
        double ysr =  yim[s], ysi = -yre[s];   // multiply by -i
        double vr = Vre[p][s], vi = Vim[p][s];
        dr += vr*ysr - vi*ysi;
        di += vr*ysi + vi*ysr;
      }
      double gg = 2.0 * (ampre[p]*dr + ampim[p]*di);   // dP_p/dw_k
      gs[p][k] = gg;
      hs[p][k] = gg * invPs[p];
    }
  }
  __syncthreads();

  // ---- M[k][m] = sum_p g[p][k] h[p][m] (the per-sample Fisher core) -------
  for (int it = 0; it < 16; ++it) {
    int idx = it * 256 + t;
    int k = idx >> 6, mm = idx & 63;
    double acc = 0.0;
    #pragma unroll
    for (int p = 0; p < 8; ++p) acc += gs[p][k] * hs[p][mm];
    Mf[k][mm] = (float)acc;
  }
  __syncthreads();

  // ---- I_b[i] = M ----------------------------------------------------------
  {
    float* ob = out + (size_t)Bn * 65536 + (size_t)i * 4096;
    for (int it = 0; it < 16; ++it) {
      int idx = it * 256 + t;
      ob[idx] = Mf[idx >> 6][idx & 63];
    }
  }
  // ---- I_k[i,j,k,l,m] = x_j x_l M[k,m], float4 streaming stores -----------
  {
    float* ok = out + (size_t)i * 65536;
    const int m4 = (t & 15) << 2;
    const int rg = t >> 4;               // 0..15
    for (int it = 0; it < 64; ++it) {
      int r = (it << 4) + rg;            // row in [0,1024): r = ((j*64+k)*4+l)
      int j = r >> 8, k = (r >> 2) & 63, l = r & 3;
      float xx = xf[j] * xf[l];
      const float4 mv = *(const float4*)&Mf[k][m4];
      float4 vv = make_float4(xx*mv.x, xx*mv.y, xx*mv.z, xx*mv.w);
      *(float4*)(ok + (size_t)r * 64 + m4) = vv;
    }
  }
}

extern "C" void kernel_launch(void* const* d_in, const int* in_sizes, int n_in,
                              void* d_out, int out_size, void* d_ws, size_t ws_size,
                              hipStream_t stream) {
  (void)n_in; (void)d_ws; (void)ws_size; (void)out_size;
  int Bn = in_sizes[0] / 4;   // 256
  fi_pauli_kernel<<<Bn, 256, 0, stream>>>(d_in[0], d_in[1], d_in[2],
                                          (float*)d_out, Bn);
}